// Round 1
// baseline (95.848 us; speedup 1.0000x reference)
//
#include <hip/hip_runtime.h>
#include <math.h>

#define B_ 4
#define Q_ 1024
#define K_ 1024
#define DIN_ 256
#define H_ 64
#define DV_ 128
#define QT 8
#define KT 64
#define MASKV -1000000.0f
#define C2LOG2E 2.8853900817779268f   // 2*log2(e): exp(2x)=exp2(C*x)
#define LOG2E 1.4426950408889634f

__device__ __forceinline__ float fexp2(float x) {
#if __has_builtin(__builtin_amdgcn_exp2f)
  return __builtin_amdgcn_exp2f(x);
#else
  return exp2f(x);
#endif
}
__device__ __forceinline__ float frcp(float x) {
#if __has_builtin(__builtin_amdgcn_rcpf)
  return __builtin_amdgcn_rcpf(x);
#else
  return 1.0f / x;
#endif
}

// Project rows: 0..B*Q-1 -> qe from (queries, Wq); B*Q.. -> ke from (keys, Wk).
// Output is pre-scaled by 2*log2(e) so score loop feeds exp2 directly.
__global__ __launch_bounds__(256) void proj_kernel(
    const float* __restrict__ queries, const float* __restrict__ keys,
    const float* __restrict__ Wq, const float* __restrict__ Wk,
    const int* __restrict__ vlen,
    float* __restrict__ qe, float* __restrict__ ke) {
  int t = threadIdx.x;
  int h = t & 63;
  int rloc = t >> 6;                 // 4 rows per block
  int row = blockIdx.x * 4 + rloc;
  const float* src;
  const float* W;
  float* dst;
  if (row < B_ * Q_) {
    src = queries + (long)row * DIN_;
    W = Wq;
    dst = qe + (long)row * H_;
  } else {
    int krow = row - B_ * Q_;
    int b = krow >> 10;
    int kk = krow & 1023;
    if (kk >= vlen[b]) return;       // masked key rows never consumed
    src = keys + (long)krow * DIN_;
    W = Wk;
    dst = ke + (long)krow * H_;
  }
  const float4* s4 = (const float4*)src;
  float acc = 0.f;
#pragma unroll 4
  for (int d4 = 0; d4 < DIN_ / 4; ++d4) {
    float4 v = s4[d4];
    int d = d4 * 4;
    acc = fmaf(v.x, W[(d + 0) * H_ + h], acc);
    acc = fmaf(v.y, W[(d + 1) * H_ + h], acc);
    acc = fmaf(v.z, W[(d + 2) * H_ + h], acc);
    acc = fmaf(v.w, W[(d + 3) * H_ + h], acc);
  }
  dst[h] = acc * C2LOG2E;
}

// Fused scores + masked online-softmax + PV. Block = (b, tile of QT queries).
__global__ __launch_bounds__(256) void attn_kernel(
    const float* __restrict__ qe, const float* __restrict__ ke,
    const float* __restrict__ values, const float* __restrict__ wv,
    const int* __restrict__ vlen, float* __restrict__ out) {
  __shared__ float ke_s[H_][KT + 1];   // [h][k], pad -> conflict-free r/w
  __shared__ float qe_s[H_][QT + 2];   // [h][q], pad keeps float2 aligned
  __shared__ float v_s[KT][DV_];
  __shared__ float s_s[QT][KT];
  __shared__ float w2_s[H_];
  __shared__ float mrow[QT], lrow[QT], srow[QT];

  int t = threadIdx.x;
  int b = blockIdx.x >> 7;            // Q_/QT = 128 q-tiles per batch
  int qt = blockIdx.x & 127;
  int kv = vlen[b];
  int qrow0 = b * Q_ + qt * QT;

  if (t < H_) w2_s[t] = 2.0f * wv[t];
  if (t < QT) { mrow[t] = -1e38f; lrow[t] = 0.f; }
  for (int i = t; i < QT * H_; i += 256) {
    int qq = i >> 6, h = i & 63;
    qe_s[h][qq] = qe[(long)(qrow0 + qq) * H_ + h];
  }
  __syncthreads();

  float Wsum = 0.f;
#pragma unroll
  for (int h = 0; h < H_; ++h) Wsum += w2_s[h];
  Wsum *= 0.5f;                        // sum of w_v

  // PV ownership: row = t>>5 (8 rows), 4 consecutive v per thread
  int prow = t >> 5;
  int v0 = (t & 31) * 4;
  float o0 = 0.f, o1 = 0.f, o2 = 0.f, o3 = 0.f;

  // score ownership: k = t&63, query pair = 2*(t>>6)
  int k_sc = t & 63;
  int q0 = (t >> 6) * 2, q1 = q0 + 1;

  int ntiles = (kv + KT - 1) / KT;     // skip fully-masked key tiles
  const float* vbase = values + (long)b * K_ * DV_;
  const float* kebase = ke + (long)b * K_ * H_;

  for (int tile = 0; tile < ntiles; ++tile) {
    int k0 = tile * KT;
    // stage ke (transposed) and values tiles
    for (int i = t; i < KT * H_; i += 256) {
      int kk = i >> 6, h = i & 63;
      ke_s[h][kk] = kebase[(long)(k0 + kk) * H_ + h];
    }
    for (int i = t; i < KT * (DV_ / 4); i += 256) {
      int kk = i >> 5, c4 = i & 31;
      *(float4*)&v_s[kk][c4 * 4] =
          *(const float4*)&vbase[(long)(k0 + kk) * DV_ + c4 * 4];
    }
    __syncthreads();

    // scores: s = Wsum - sum_h w2[h] / (1 + exp2(qe+ke))
    float a0 = Wsum, a1 = Wsum;
#pragma unroll 16
    for (int h = 0; h < H_; ++h) {
      float kev = ke_s[h][k_sc];
      float w2 = w2_s[h];
      float qa = qe_s[h][q0];
      float qb = qe_s[h][q1];
      float r0 = frcp(1.f + fexp2(kev + qa));
      float r1 = frcp(1.f + fexp2(kev + qb));
      a0 = fmaf(-w2, r0, a0);
      a1 = fmaf(-w2, r1, a1);
    }
    bool valid = (k0 + k_sc) < kv;
    s_s[q0][k_sc] = valid ? a0 : MASKV;
    s_s[q1][k_sc] = valid ? a1 : MASKV;
    __syncthreads();

    // online softmax update: 32 lanes per row, 2 keys each
    {
      int l = t & 31;
      float x0 = s_s[prow][l], x1 = s_s[prow][l + 32];
      float mt = fmaxf(x0, x1);
#pragma unroll
      for (int m = 16; m >= 1; m >>= 1) mt = fmaxf(mt, __shfl_xor(mt, m));
      float mold = mrow[prow];
      float mnew = fmaxf(mold, mt);
      float p0 = fexp2((x0 - mnew) * LOG2E);
      float p1 = fexp2((x1 - mnew) * LOG2E);
      s_s[prow][l] = p0;
      s_s[prow][l + 32] = p1;
      float ps = p0 + p1;
#pragma unroll
      for (int m = 16; m >= 1; m >>= 1) ps += __shfl_xor(ps, m);
      if (l == 0) {
        float sc = fexp2((mold - mnew) * LOG2E);
        srow[prow] = sc;
        lrow[prow] = lrow[prow] * sc + ps;
        mrow[prow] = mnew;
      }
    }
    __syncthreads();

    // PV accumulate
    float sc = srow[prow];
    o0 *= sc; o1 *= sc; o2 *= sc; o3 *= sc;
#pragma unroll 8
    for (int kk = 0; kk < KT; ++kk) {
      float p = s_s[prow][kk];
      float4 vvv = *(const float4*)&v_s[kk][v0];
      o0 = fmaf(p, vvv.x, o0);
      o1 = fmaf(p, vvv.y, o1);
      o2 = fmaf(p, vvv.z, o2);
      o3 = fmaf(p, vvv.w, o3);
    }
    __syncthreads();
  }

  float inv = 1.0f / lrow[prow];
  float4 res;
  res.x = o0 * inv; res.y = o1 * inv; res.z = o2 * inv; res.w = o3 * inv;
  *(float4*)&out[(long)(qrow0 + prow) * DV_ + v0] = res;
}

extern "C" void kernel_launch(void* const* d_in, const int* in_sizes, int n_in,
                              void* d_out, int out_size, void* d_ws, size_t ws_size,
                              hipStream_t stream) {
  const float* queries = (const float*)d_in[0];
  const float* keys    = (const float*)d_in[1];
  const float* values  = (const float*)d_in[2];
  const int*   vl      = (const int*)d_in[3];
  const float* Wq      = (const float*)d_in[4];
  const float* Wk      = (const float*)d_in[5];
  const float* wv      = (const float*)d_in[6];
  float* out = (float*)d_out;

  float* qe = (float*)d_ws;                       // B*Q*H floats = 1 MB
  float* ke = qe + (size_t)B_ * Q_ * H_;          // B*K*H floats = 1 MB

  proj_kernel<<<dim3((B_ * Q_ + B_ * K_) / 4), dim3(256), 0, stream>>>(
      queries, keys, Wq, Wk, vl, qe, ke);
  attn_kernel<<<dim3(B_ * (Q_ / QT)), dim3(256), 0, stream>>>(
      qe, ke, values, wv, vl, out);
}

// Round 2
// 89.720 us; speedup vs baseline: 1.0683x; 1.0683x over previous
//
#include <hip/hip_runtime.h>
#include <math.h>

#define B_ 4
#define Q_ 1024
#define K_ 1024
#define DIN_ 256
#define H_ 64
#define DV_ 128
#define QT 4
#define KT 64
#define MASKV -1000000.0f
#define C2LOG2E 2.8853900817779268f   // 2*log2(e): exp(2x)=exp2(C*x)
#define LOG2E 1.4426950408889634f

__device__ __forceinline__ float fexp2(float x) {
#if __has_builtin(__builtin_amdgcn_exp2f)
  return __builtin_amdgcn_exp2f(x);
#else
  return exp2f(x);
#endif
}
__device__ __forceinline__ float frcp(float x) {
#if __has_builtin(__builtin_amdgcn_rcpf)
  return __builtin_amdgcn_rcpf(x);
#else
  return 1.0f / x;
#endif
}

// Project rows and exponentiate: EQ = exp2(C*(q·Wq)), EK = exp2(C*(k·Wk)).
// Then 1+e^{2(q+k)} = 1 + EQ*EK -> score loop needs only fma+rcp+fma.
__global__ __launch_bounds__(256) void proj_kernel(
    const float* __restrict__ queries, const float* __restrict__ keys,
    const float* __restrict__ Wq, const float* __restrict__ Wk,
    const int* __restrict__ vlen,
    float* __restrict__ eq, float* __restrict__ ek) {
  int t = threadIdx.x;
  int h = t & 63;
  int row = blockIdx.x * 4 + (t >> 6);
  const float* src;
  const float* W;
  float* dst;
  if (row < B_ * Q_) {
    src = queries + (long)row * DIN_;
    W = Wq;
    dst = eq + (long)row * H_;
  } else {
    int krow = row - B_ * Q_;
    int b = krow >> 10, kk = krow & 1023;
    if (kk >= vlen[b]) return;       // masked key rows never consumed
    src = keys + (long)krow * DIN_;
    W = Wk;
    dst = ek + (long)krow * H_;
  }
  const float4* s4 = (const float4*)src;
  float a0 = 0.f, a1 = 0.f, a2 = 0.f, a3 = 0.f;  // 4 chains: break fma latency
#pragma unroll 8
  for (int d4 = 0; d4 < DIN_ / 4; ++d4) {
    float4 v = s4[d4];
    int d = d4 * 4;
    a0 = fmaf(v.x, W[(d + 0) * H_ + h], a0);
    a1 = fmaf(v.y, W[(d + 1) * H_ + h], a1);
    a2 = fmaf(v.z, W[(d + 2) * H_ + h], a2);
    a3 = fmaf(v.w, W[(d + 3) * H_ + h], a3);
  }
  dst[h] = fexp2(((a0 + a1) + (a2 + a3)) * C2LOG2E);
}

// Fused scores + masked online-softmax + PV.
// Block = (b, tile of QT=4 queries); each wave owns ONE query row ->
// softmax state (m,l) is wave-local registers, no cross-wave sync beyond
// the ek_s staging barriers. PV reads values straight from global (L2-res).
__global__ __launch_bounds__(256) void attn_kernel(
    const float* __restrict__ eq, const float* __restrict__ ek,
    const float* __restrict__ values, const float* __restrict__ wv,
    const int* __restrict__ vlen, float* __restrict__ out) {
  __shared__ float ek_s[H_][KT + 1];   // [h][k], pad -> conflict-free
  __shared__ float p_s[QT][KT];        // per-wave p broadcast row

  int t = threadIdx.x;
  int lane = t & 63;
  int w = t >> 6;                      // wave id == local query index
  int b = blockIdx.x >> 8;             // Q_/QT = 256 tiles per batch
  int qt = blockIdx.x & 255;
  int kv = vlen[b];
  int qrow = b * Q_ + qt * QT + w;
  int wrow = __builtin_amdgcn_readfirstlane(qrow);  // force SGPR base
  const float* eqrow = eq + (long)wrow * H_;        // -> s_load in loop

  float wsum = 0.f;                    // sum of w_v (uniform s_loads)
#pragma unroll
  for (int h = 0; h < H_; ++h) wsum += wv[h];

  float m = -1e38f, l = 0.f;
  float o0 = 0.f, o1 = 0.f;            // lane owns out cols 2*lane, 2*lane+1
  int ntiles = (kv + KT - 1) / KT;     // skip fully-masked key tiles
  const float* ekbase = ek + (long)b * K_ * H_;
  const float* vbase = values + (long)b * K_ * DV_ + lane * 2;

  for (int tile = 0; tile < ntiles; ++tile) {
    int k0 = tile * KT;
    __syncthreads();                   // prior tile's readers done
    for (int i = t; i < KT * H_; i += 256) {
      int kk = i >> 6, h = i & 63;
      ek_s[h][kk] = ekbase[(long)(k0 + kk) * H_ + h];
    }
    __syncthreads();

    // score: x = wsum - 2 * sum_h wv[h] / (1 + EQ[h]*EK[h][k])
    float acc = 0.f;
#pragma unroll 16
    for (int h = 0; h < H_; ++h) {
      float r = frcp(fmaf(eqrow[h], ek_s[h][lane], 1.0f));
      acc = fmaf(wv[h], r, acc);
    }
    float x = fmaf(-2.0f, acc, wsum);
    if (k0 + lane >= kv) x = MASKV;

    // wave-local online softmax (64-lane reduces)
    float mt = x;
#pragma unroll
    for (int s = 32; s >= 1; s >>= 1) mt = fmaxf(mt, __shfl_xor(mt, s));
    float mnew = fmaxf(m, mt);
    float p = fexp2((x - mnew) * LOG2E);
    float ps = p;
#pragma unroll
    for (int s = 32; s >= 1; s >>= 1) ps += __shfl_xor(ps, s);
    float sc = fexp2((m - mnew) * LOG2E);
    l = l * sc + ps;
    m = mnew;
    o0 *= sc;
    o1 *= sc;
    p_s[w][lane] = p;                  // same-wave write->read, no barrier

    // PV accumulate: p broadcast from LDS, V rows from global (coalesced)
#pragma unroll 4
    for (int kk4 = 0; kk4 < KT / 4; ++kk4) {
      float4 p4 = *(const float4*)&p_s[w][kk4 * 4];
      const float* vr = vbase + (long)(k0 + kk4 * 4) * DV_;
      float2 v0 = *(const float2*)(vr);
      float2 v1 = *(const float2*)(vr + DV_);
      float2 v2 = *(const float2*)(vr + 2 * DV_);
      float2 v3 = *(const float2*)(vr + 3 * DV_);
      o0 = fmaf(p4.x, v0.x, o0); o1 = fmaf(p4.x, v0.y, o1);
      o0 = fmaf(p4.y, v1.x, o0); o1 = fmaf(p4.y, v1.y, o1);
      o0 = fmaf(p4.z, v2.x, o0); o1 = fmaf(p4.z, v2.y, o1);
      o0 = fmaf(p4.w, v3.x, o0); o1 = fmaf(p4.w, v3.y, o1);
    }
  }

  float inv = frcp(l);
  float2 res;
  res.x = o0 * inv;
  res.y = o1 * inv;
  *(float2*)&out[(long)qrow * DV_ + lane * 2] = res;
}

extern "C" void kernel_launch(void* const* d_in, const int* in_sizes, int n_in,
                              void* d_out, int out_size, void* d_ws, size_t ws_size,
                              hipStream_t stream) {
  const float* queries = (const float*)d_in[0];
  const float* keys    = (const float*)d_in[1];
  const float* values  = (const float*)d_in[2];
  const int*   vl      = (const int*)d_in[3];
  const float* Wq      = (const float*)d_in[4];
  const float* Wk      = (const float*)d_in[5];
  const float* wv      = (const float*)d_in[6];
  float* out = (float*)d_out;

  float* eq = (float*)d_ws;                       // B*Q*H floats = 1 MB
  float* ek = eq + (size_t)B_ * Q_ * H_;          // B*K*H floats = 1 MB

  proj_kernel<<<dim3((B_ * Q_ + B_ * K_) / 4), dim3(256), 0, stream>>>(
      queries, keys, Wq, Wk, vl, eq, ek);
  attn_kernel<<<dim3(B_ * (Q_ / QT)), dim3(256), 0, stream>>>(
      eq, ek, values, wv, vl, out);
}

// Round 3
// 53.120 us; speedup vs baseline: 1.8044x; 1.6890x over previous
//
#include <hip/hip_runtime.h>
#include <math.h>

#define B_ 4
#define Q_ 1024
#define K_ 1024
#define DIN_ 256
#define H_ 64
#define DV_ 128
#define KT 64
#define MASKV -1000000.0f
#define C2LOG2E 2.8853900817779268f   // 2*log2(e): exp(2x)=exp2(C*x)
#define LOG2E 1.4426950408889634f

__device__ __forceinline__ float fexp2(float x) {
#if __has_builtin(__builtin_amdgcn_exp2f)
  return __builtin_amdgcn_exp2f(x);
#else
  return exp2f(x);
#endif
}
__device__ __forceinline__ float frcp(float x) {
#if __has_builtin(__builtin_amdgcn_rcpf)
  return __builtin_amdgcn_rcpf(x);
#else
  return 1.0f / x;
#endif
}
__device__ __forceinline__ float bitsf(unsigned u) { return __uint_as_float(u); }
__device__ __forceinline__ unsigned short f2bf(float f) {  // RNE float->bf16
  unsigned u = __float_as_uint(f);
  return (unsigned short)((u + 0x7FFFu + ((u >> 16) & 1u)) >> 16);
}

// blocks [0,512): row projections EQ/EK = exp2(C * row.W), 16 rows/block
//   (4 rows per wave, lane = h; W element reused across 4 rows).
// blocks [512,1024): values -> bf16 (packed, RNE).
__global__ __launch_bounds__(256, 4) void prep_kernel(
    const float* __restrict__ queries, const float* __restrict__ keys,
    const float* __restrict__ values,
    const float* __restrict__ Wq, const float* __restrict__ Wk,
    float* __restrict__ eq, float* __restrict__ ek,
    unsigned short* __restrict__ vb) {
  int bid = blockIdx.x;
  int t = threadIdx.x;
  if (bid >= 512) {
    int i = ((bid - 512) * 256 + t) * 4;     // 512*256*4 = 524288 = B*K*DV
    float4 v = *(const float4*)&values[i];
    ushort4 o;
    o.x = f2bf(v.x); o.y = f2bf(v.y); o.z = f2bf(v.z); o.w = f2bf(v.w);
    *(ushort4*)&vb[i] = o;
    return;
  }
  int w = t >> 6, lane = t & 63;
  int r0 = __builtin_amdgcn_readfirstlane(bid * 16 + w * 4);  // rows r0..r0+3
  const float* src;
  const float* W;
  float* dst;
  if (r0 < B_ * Q_) {
    src = queries + r0 * DIN_; W = Wq; dst = eq + r0 * H_;
  } else {
    int kr = r0 - B_ * Q_;
    src = keys + kr * DIN_; W = Wk; dst = ek + kr * H_;
  }
  float a00 = 0.f, a01 = 0.f, a10 = 0.f, a11 = 0.f;
  float a20 = 0.f, a21 = 0.f, a30 = 0.f, a31 = 0.f;
#pragma unroll 8
  for (int d = 0; d < DIN_; d += 2) {
    float w0 = W[d * H_ + lane];
    float w1 = W[(d + 1) * H_ + lane];
    a00 = fmaf(w0, src[d], a00);             a01 = fmaf(w1, src[d + 1], a01);
    a10 = fmaf(w0, src[DIN_ + d], a10);      a11 = fmaf(w1, src[DIN_ + d + 1], a11);
    a20 = fmaf(w0, src[2 * DIN_ + d], a20);  a21 = fmaf(w1, src[2 * DIN_ + d + 1], a21);
    a30 = fmaf(w0, src[3 * DIN_ + d], a30);  a31 = fmaf(w1, src[3 * DIN_ + d + 1], a31);
  }
  dst[lane]          = fexp2((a00 + a01) * C2LOG2E);
  dst[H_ + lane]     = fexp2((a10 + a11) * C2LOG2E);
  dst[2 * H_ + lane] = fexp2((a20 + a21) * C2LOG2E);
  dst[3 * H_ + lane] = fexp2((a30 + a31) * C2LOG2E);
}

// Barrier-free flash attention. Wave owns 2 queries; lane owns 1 key slot.
// ek row lives in 64 registers; eq/wv come through scalar loads; p broadcast
// via wave-private LDS row (same-wave lgkmcnt only, no __syncthreads).
__global__ __launch_bounds__(256, 2) void attn_kernel(
    const float* __restrict__ eq, const float* __restrict__ ek,
    const unsigned* __restrict__ vb32, const float* __restrict__ wv,
    const int* __restrict__ vlen, float* __restrict__ out) {
  __shared__ __align__(16) float p_s[4][2][KT];
  int t = threadIdx.x;
  int lane = t & 63;
  int w = t >> 6;
  int bid = blockIdx.x;
  int b = bid >> 7;                           // 128 blocks per batch
  int q0 = __builtin_amdgcn_readfirstlane(((bid & 127) * 4 + w) * 2);
  int kv = vlen[b];
  const float* eqa = eq + (b * Q_ + q0) * H_;
  const float* eqb = eqa + H_;
  const float* ekb = ek + b * K_ * H_;
  const unsigned* vbb = vb32 + b * K_ * (DV_ / 2) + lane;  // + row*64

  float wsum = 0.f;
#pragma unroll
  for (int h = 0; h < H_; ++h) wsum += wv[h];

  float ma = -1e38f, mb = -1e38f, la = 0.f, lb = 0.f;
  float oa0 = 0.f, oa1 = 0.f, ob0 = 0.f, ob1 = 0.f;
  int ntiles = (kv + KT - 1) >> 6;

  for (int tile = 0; tile < ntiles; ++tile) {
    int k0 = tile * KT;
    // ek row for this lane's key -> 64 registers (L1-resident dwordx4 loads)
    const float4* ekr4 = (const float4*)(ekb + (k0 + lane) * H_);
    float ekf[64];
#pragma unroll
    for (int j = 0; j < 16; ++j) {
      float4 tv = ekr4[j];
      ekf[j * 4] = tv.x; ekf[j * 4 + 1] = tv.y;
      ekf[j * 4 + 2] = tv.z; ekf[j * 4 + 3] = tv.w;
    }
    // scores: x = wsum - 2 * sum_h wv[h] / (1 + EQ[h]*EK[h])  (pure compute)
    float aa0 = 0.f, aa1 = 0.f, ab0 = 0.f, ab1 = 0.f;
#pragma unroll
    for (int h = 0; h < H_; ++h) {
      float ekv = ekf[h];
      float wvh = wv[h];
      float ra = frcp(fmaf(ekv, eqa[h], 1.0f));
      float rb = frcp(fmaf(ekv, eqb[h], 1.0f));
      if (h & 1) { aa1 = fmaf(wvh, ra, aa1); ab1 = fmaf(wvh, rb, ab1); }
      else       { aa0 = fmaf(wvh, ra, aa0); ab0 = fmaf(wvh, rb, ab0); }
    }
    float xa = fmaf(-2.f, aa0 + aa1, wsum);
    float xb = fmaf(-2.f, ab0 + ab1, wsum);
    if (k0 + lane >= kv) { xa = MASKV; xb = MASKV; }

    // wave-local online softmax for both queries (interleaved reduces)
    float mta = xa, mtb = xb;
#pragma unroll
    for (int s = 32; s >= 1; s >>= 1) {
      mta = fmaxf(mta, __shfl_xor(mta, s));
      mtb = fmaxf(mtb, __shfl_xor(mtb, s));
    }
    float mna = fmaxf(ma, mta), mnb = fmaxf(mb, mtb);
    float pa = fexp2((xa - mna) * LOG2E);
    float pb = fexp2((xb - mnb) * LOG2E);
    float psa = pa, psb = pb;
#pragma unroll
    for (int s = 32; s >= 1; s >>= 1) {
      psa += __shfl_xor(psa, s);
      psb += __shfl_xor(psb, s);
    }
    float sca = fexp2((ma - mna) * LOG2E);
    float scb = fexp2((mb - mnb) * LOG2E);
    la = fmaf(la, sca, psa); lb = fmaf(lb, scb, psb);
    ma = mna; mb = mnb;
    oa0 *= sca; oa1 *= sca; ob0 *= scb; ob1 *= scb;
    p_s[w][0][lane] = pa;
    p_s[w][1][lane] = pb;   // same-wave write->read; compiler inserts lgkmcnt

    // PV: p broadcast from wave-private LDS, V as packed bf16 pairs
#pragma unroll 4
    for (int k4 = 0; k4 < KT / 4; ++k4) {
      float4 pa4 = *(const float4*)&p_s[w][0][k4 * 4];
      float4 pb4 = *(const float4*)&p_s[w][1][k4 * 4];
      int r = (k0 + k4 * 4) * (DV_ / 2);
      unsigned vv0 = vbb[r];
      unsigned vv1 = vbb[r + 64];
      unsigned vv2 = vbb[r + 128];
      unsigned vv3 = vbb[r + 192];
      float v00 = bitsf(vv0 << 16), v01 = bitsf(vv0 & 0xFFFF0000u);
      float v10 = bitsf(vv1 << 16), v11 = bitsf(vv1 & 0xFFFF0000u);
      float v20 = bitsf(vv2 << 16), v21 = bitsf(vv2 & 0xFFFF0000u);
      float v30 = bitsf(vv3 << 16), v31 = bitsf(vv3 & 0xFFFF0000u);
      oa0 = fmaf(pa4.x, v00, oa0); oa1 = fmaf(pa4.x, v01, oa1);
      ob0 = fmaf(pb4.x, v00, ob0); ob1 = fmaf(pb4.x, v01, ob1);
      oa0 = fmaf(pa4.y, v10, oa0); oa1 = fmaf(pa4.y, v11, oa1);
      ob0 = fmaf(pb4.y, v10, ob0); ob1 = fmaf(pb4.y, v11, ob1);
      oa0 = fmaf(pa4.z, v20, oa0); oa1 = fmaf(pa4.z, v21, oa1);
      ob0 = fmaf(pb4.z, v20, ob0); ob1 = fmaf(pb4.z, v21, ob1);
      oa0 = fmaf(pa4.w, v30, oa0); oa1 = fmaf(pa4.w, v31, oa1);
      ob0 = fmaf(pb4.w, v30, ob0); ob1 = fmaf(pb4.w, v31, ob1);
    }
  }

  float ia = frcp(la), ib = frcp(lb);
  int obase = (b * Q_ + q0) * DV_ + lane * 2;
  *(float2*)&out[obase] = make_float2(oa0 * ia, oa1 * ia);
  *(float2*)&out[obase + DV_] = make_float2(ob0 * ib, ob1 * ib);
}

extern "C" void kernel_launch(void* const* d_in, const int* in_sizes, int n_in,
                              void* d_out, int out_size, void* d_ws, size_t ws_size,
                              hipStream_t stream) {
  const float* queries = (const float*)d_in[0];
  const float* keys    = (const float*)d_in[1];
  const float* values  = (const float*)d_in[2];
  const int*   vl      = (const int*)d_in[3];
  const float* Wq      = (const float*)d_in[4];
  const float* Wk      = (const float*)d_in[5];
  const float* wv      = (const float*)d_in[6];
  float* out = (float*)d_out;

  float* eq = (float*)d_ws;                          // 4096*64 f = 1 MB
  float* ek = eq + (size_t)B_ * Q_ * H_;             // 4096*64 f = 1 MB
  unsigned short* vb = (unsigned short*)(ek + (size_t)B_ * K_ * H_);  // 1 MB bf16

  prep_kernel<<<dim3(1024), dim3(256), 0, stream>>>(
      queries, keys, values, Wq, Wk, eq, ek, vb);
  attn_kernel<<<dim3(B_ * (Q_ / 8)), dim3(256), 0, stream>>>(
      eq, ek, (const unsigned*)vb, wv, vl, out);
}